// Round 7
// baseline (114.390 us; speedup 1.0000x reference)
//
#include <hip/hip_runtime.h>
#include <math.h>

#define PP 3072
#define NB 15
#define NM 8
#define BIGF 1e30f

// ws layout (bytes):
//  sums:   [0, 960)          float[2][15][8]
//  counts: [960, 1440)       int[15][8]
//  bits:   [1536, 47616)     uchar[15][3072]   x-side mask byte
//  sidx:   [47616, 139776)   ushort[15][3072]  y-order sorted by mask byte
//  rend:   [139776, 147456)  ushort[15][256]   run end offsets (exclusive)
//  rbyte:  [147456, 151296)  uchar[15][256]    run byte values
//  segf:   [151296, 151416)  uchar[15][8]      first run idx per wave segment
#define WS_SUMS 0
#define WS_COUNTS 960
#define WS_BITS 1536
#define WS_SIDX 47616
#define WS_REND 139776
#define WS_RBYTE 147456
#define WS_SEGF 151296

__global__ __launch_bounds__(1024) void sort_kernel(
    const void* __restrict__ mask, unsigned char* __restrict__ bits,
    unsigned short* __restrict__ sidx, unsigned short* __restrict__ rend,
    unsigned char* __restrict__ rbyte, unsigned char* __restrict__ segf,
    int* __restrict__ counts, float* __restrict__ sums) {
  const int b = blockIdx.x;
  const int tid = threadIdx.x;
  __shared__ int hist[256];
  __shared__ int scanbuf[256];
  __shared__ int pfx[257];
  __shared__ int rankbuf[256];
  __shared__ int cnt[256];
  if (tid < 256) { hist[tid] = 0; cnt[tid] = 0; }
  if (tid < 2 * NM) sums[(tid >> 3) * NB * NM + b * NM + (tid & 7)] = 0.f;

  // mask element-width probe: for int32 {0,1} masks, bytes 1..3 of each dword
  // are zero over the first 64 bytes; for random bool bytes P(all zero)=2^-48.
  const uint4* pw = (const uint4*)mask;
  uint4 w0 = pw[0], w1 = pw[1], w2 = pw[2], w3 = pw[3];
  unsigned acc = (w0.x | w0.y | w0.z | w0.w | w1.x | w1.y | w1.z | w1.w |
                  w2.x | w2.y | w2.z | w2.w | w3.x | w3.y | w3.z | w3.w) &
                 0xFFFFFF00u;
  const bool bytemode = (acc != 0);
  const unsigned char* mb = (const unsigned char*)mask;
  const int* mi = (const int*)mask;

  unsigned char mybyte[3];
  __syncthreads();
#pragma unroll
  for (int k = 0; k < 3; k++) {
    int p = k * 1024 + tid;
    unsigned v = 0;
#pragma unroll
    for (int m = 0; m < NM; m++) {
      long q = (long)(b * NM + m) * PP + p;
      unsigned bit = bytemode ? (mb[q] != 0) : (mi[q] != 0);
      v |= bit << m;
    }
    mybyte[k] = (unsigned char)v;
    bits[b * PP + p] = (unsigned char)v;
    atomicAdd(&hist[v], 1);
  }
  __syncthreads();

  // inclusive scan of hist -> pfx ; inclusive scan of (hist>0) -> rankbuf
  if (tid < 256) { scanbuf[tid] = hist[tid]; rankbuf[tid] = hist[tid] > 0; }
  __syncthreads();
  for (int off = 1; off < 256; off <<= 1) {
    int v = 0, u = 0;
    if (tid < 256 && tid >= off) { v = scanbuf[tid - off]; u = rankbuf[tid - off]; }
    __syncthreads();
    if (tid < 256 && tid >= off) { scanbuf[tid] += v; rankbuf[tid] += u; }
    __syncthreads();
  }
  if (tid == 0) pfx[0] = 0;
  if (tid < 256) pfx[tid + 1] = scanbuf[tid];
  __syncthreads();

  // per-part counts straight from the histogram
  if (tid < NM) {
    int s = 0;
    for (int v = 0; v < 256; v++)
      if ((v >> tid) & 1) s += hist[v];
    counts[b * NM + tid] = s;
  }
  // run table (ordered by byte value = sorted order)
  if (tid < 256 && hist[tid] > 0) {
    int rk = rankbuf[tid] - 1;  // inclusive -> exclusive
    rend[b * 256 + rk] = (unsigned short)pfx[tid + 1];
    rbyte[b * 256 + rk] = (unsigned char)tid;
  }
  // first run index per 384-point wave segment
  if (tid < NM) {
    int ys = tid * 384, c = 0;
    for (int v = 0; v < 256; v++)
      c += (hist[v] > 0 && pfx[v + 1] <= ys) ? 1 : 0;
    segf[b * NM + tid] = (unsigned char)c;
  }
  // scatter point indices into sorted order (intra-run order irrelevant)
#pragma unroll
  for (int k = 0; k < 3; k++) {
    int p = k * 1024 + tid;
    unsigned v = mybyte[k];
    int rank = pfx[v] + atomicAdd(&cnt[v], 1);
    sidx[b * PP + rank] = (unsigned short)p;
  }
}

__global__ __launch_bounds__(512) void chamfer_main(
    const float* __restrict__ pred, const float* __restrict__ gt,
    const unsigned char* __restrict__ bits,
    const unsigned short* __restrict__ sidx,
    const unsigned short* __restrict__ rend,
    const unsigned char* __restrict__ rbyte,
    const unsigned char* __restrict__ segf,
    float* __restrict__ sums) {
  const int b = blockIdx.y;
  const int dir = blockIdx.z;
  const float* __restrict__ own = dir ? gt : pred;
  const float* __restrict__ oth = dir ? pred : gt;
  const int tid = threadIdx.x;
  const int lane = tid & 63;
  const int w = tid >> 6;

  __shared__ float4 tile[PP];             // 48 KB sorted y points
  __shared__ unsigned minbuf[NM][128];    // 4 KB per-x per-m min(d^2)
  __shared__ unsigned runtab[256];        // 1 KB packed (end<<8)|byte

  for (int i = tid; i < NM * 128; i += 512)
    ((unsigned*)minbuf)[i] = 0x7F7FFFFFu;
  if (tid < 256)
    runtab[tid] = ((unsigned)rend[b * 256 + tid] << 8) | rbyte[b * 256 + tid];

  for (int j = tid; j < PP; j += 512) {
    int idx = sidx[b * PP + j];
    const float* q = &oth[((long)b * PP + idx) * 3];
    float4 v;
    v.x = q[0]; v.y = q[1]; v.z = q[2]; v.w = 0.f;
    tile[j] = v;
  }

  const int x0 = blockIdx.x * 128 + lane;
  const long gx0 = (long)b * PP + x0;
  const long gx1 = gx0 + 64;
  const float ax = own[gx0 * 3 + 0], ay = own[gx0 * 3 + 1], az = own[gx0 * 3 + 2];
  const float bx = own[gx1 * 3 + 0], by = own[gx1 * 3 + 1], bz = own[gx1 * 3 + 2];
  const unsigned mb0 = bits[gx0], mb1 = bits[gx1];

  __syncthreads();

  const int ys = w * 384, ye = ys + 384;
  int r = __builtin_amdgcn_readfirstlane(segf[b * NM + w]);
  int j = ys;

  while (j < ye) {
    const unsigned pk = __builtin_amdgcn_readfirstlane(runtab[r]);
    const int e = (int)(pk >> 8);
    const unsigned byte = pk & 0xFFu;
    const int e2 = e < ye ? e : ye;
    float dmin0 = BIGF, dmin1 = BIGF;
    // tight inner loop: 1 uniform ds_read_b128 + 12 dist VALU + 2 fmin
    for (; j < e2; j++) {
      float4 v = tile[j];
      float dx = ax - v.x, dy = ay - v.y, dz = az - v.z;
      float d0 = fmaf(dz, dz, fmaf(dy, dy, dx * dx));
      float ex = bx - v.x, ey = by - v.y, ez = bz - v.z;
      float d1 = fmaf(ez, ez, fmaf(ey, ey, ex * ex));
      dmin0 = fminf(dmin0, d0);
      dmin1 = fminf(dmin1, d1);
    }
    // run-boundary merge via LDS atomics: side effects can't be speculated,
    // if-converted, or flattened into the inner loop.
#pragma unroll
    for (int m = 0; m < NM; m++)
      if ((byte >> m) & 1) {
        atomicMin(&minbuf[m][lane], __float_as_uint(dmin0));
        atomicMin(&minbuf[m][lane + 64], __float_as_uint(dmin1));
      }
    r++;
  }

  __syncthreads();

  if (w == 0) {
#pragma unroll
    for (int m = 0; m < NM; m++) {
      float s0 = sqrtf(__uint_as_float(minbuf[m][lane]));
      float s1 = sqrtf(__uint_as_float(minbuf[m][lane + 64]));
      float t = (((mb0 >> m) & 1) ? s0 : 0.f) + (((mb1 >> m) & 1) ? s1 : 0.f);
      for (int off = 32; off > 0; off >>= 1) t += __shfl_down(t, off);
      if (lane == 0) atomicAdd(&sums[(dir * NB + b) * NM + m], t);
    }
  }
}

__global__ void chamfer_final(const float* __restrict__ sums,
                              const int* __restrict__ counts,
                              float* __restrict__ out) {
  const int lane = threadIdx.x;
  float obj = 0.f;
  int cv = 0;
  if (lane < NB) {
    float objsum = 0.f;
    int nvalid = 0;
#pragma unroll
    for (int m = 0; m < NM; m++) {
      int n = counts[lane * NM + m];
      int dn = n > 1 ? n : 1;
      float ch = 0.5f * (sums[(0 * NB + lane) * NM + m] +
                         sums[(1 * NB + lane) * NM + m]) / (float)dn;
      if (n >= 2) { nvalid++; objsum += ch; }
    }
    if (nvalid > 0) { obj = objsum / (float)nvalid; cv = 1; }
  }
  for (int off = 32; off > 0; off >>= 1) {
    obj += __shfl_down(obj, off);
    cv += __shfl_down(cv, off);
  }
  if (lane == 0) out[0] = cv > 0 ? obj / (float)cv : 0.f;
}

extern "C" void kernel_launch(void* const* d_in, const int* in_sizes, int n_in,
                              void* d_out, int out_size, void* d_ws, size_t ws_size,
                              hipStream_t stream) {
  const float* pred = (const float*)d_in[0];
  const float* gt = (const float*)d_in[1];
  const void* mask = d_in[3];

  char* ws = (char*)d_ws;
  float* sums = (float*)(ws + WS_SUMS);
  int* counts = (int*)(ws + WS_COUNTS);
  unsigned char* bits = (unsigned char*)(ws + WS_BITS);
  unsigned short* sidx = (unsigned short*)(ws + WS_SIDX);
  unsigned short* rend = (unsigned short*)(ws + WS_REND);
  unsigned char* rbyte = (unsigned char*)(ws + WS_RBYTE);
  unsigned char* segf = (unsigned char*)(ws + WS_SEGF);
  float* out = (float*)d_out;

  sort_kernel<<<NB, 1024, 0, stream>>>(mask, bits, sidx, rend, rbyte, segf,
                                       counts, sums);
  chamfer_main<<<dim3(24, NB, 2), 512, 0, stream>>>(pred, gt, bits, sidx, rend,
                                                    rbyte, segf, sums);
  chamfer_final<<<1, 64, 0, stream>>>(sums, counts, out);
}